// Round 3
// baseline (875.155 us; speedup 1.0000x reference)
//
#include <hip/hip_runtime.h>
#include <hip/hip_bf16.h>
#include <math.h>

typedef __hip_bfloat16 bf16;
typedef __attribute__((ext_vector_type(8))) short s8v;   // 8 bf16 = 4 VGPR (MFMA A/B frag)
typedef __attribute__((ext_vector_type(4))) float f4v;   // MFMA C/D frag

// B=256, S=32, D=512, HW=196
#define BB 256
#define SS 32
#define DD 512
#define HWN 196
#define PKP 520   // pk LDS row pitch (bf16): 1040B -> 4-bank row step, 2-way (free) frag reads
#define SGP 72    // staging LDS row pitch (bf16): 144B -> 4-bank step, 2-way frag reads

__device__ __forceinline__ float b2f(bf16 x){ return __bfloat162float(x); }
__device__ __forceinline__ bf16 f2b(float x){ return __float2bfloat16(x); }
__device__ __forceinline__ float us2f(unsigned short u){
    union { unsigned int i; float f; } t; t.i = ((unsigned int)u) << 16; return t.f;
}
// dt: 1 = inputs are bf16, 0 = inputs are fp32 (runtime-uniform)
__device__ __forceinline__ float ldin(int dt, const void* p, size_t i){
    return dt ? b2f(((const bf16*)p)[i]) : ((const float*)p)[i];
}

// ---------------- dtype detector ----------------
__global__ void detect_k(const void* q, int* flag){
    __shared__ int cnt;
    if (threadIdx.x == 0) cnt = 0;
    __syncthreads();
    const unsigned short* u = (const unsigned short*)q;
    unsigned short v = u[threadIdx.x * 4];
    int e = (v >> 7) & 0xFF;
    atomicAdd(&cnt, (e >= 100 && e <= 140) ? 1 : 0);
    __syncthreads();
    if (threadIdx.x == 0) *flag = (cnt > 128) ? 1 : 0;
}

// ---------------- fused weight prep (runtime dt; per-dtype alt pointers) ----------------
struct PJob { const void* s; const void* s_b; const void* s2; const void* s2_b;
              bf16* d; int R, C, ldd, kofs, mode, boff; };
struct PrepP { PJob j[11]; const void* war; const void* bk; float* warf; float* bkf; };

__global__ __launch_bounds__(256) void prep_k(PrepP P, const int* __restrict__ flag){
    const int dt = *flag;
    __shared__ float T[32][33];
    int bx = blockIdx.x;
    int ji = 0;
    #pragma unroll
    for (int i = 0; i < 11; ++i) if (bx >= P.j[i].boff) ji = i;
    PJob jb = P.j[ji];
    const void* src  = dt ? jb.s_b  : jb.s;
    const void* src2 = dt ? jb.s2_b : jb.s2;
    int t = bx - jb.boff;
    int tx = threadIdx.x & 31, ty = threadIdx.x >> 5;
    if (jb.mode == 3){
        for (int i = threadIdx.x; i < DD; i += 256){
            P.warf[i] = ldin(dt, P.war, i);
            P.bkf[i]  = ldin(dt, P.bk, i);
        }
        return;
    }
    int nrt = jb.R >> 5;
    int r0 = (t % nrt) << 5, c0 = (t / nrt) << 5;
    if (jb.mode == 2){
        for (int rr = ty; rr < 32; rr += 8)
            jb.d[(size_t)(r0 + rr) * jb.ldd + jb.kofs + c0 + tx] =
                f2b(ldin(dt, src, (size_t)(r0 + rr) * jb.C + c0 + tx));
        return;
    }
    for (int rr = ty; rr < 32; rr += 8){
        float v = ldin(dt, src, (size_t)(r0 + rr) * jb.C + c0 + tx);
        if (jb.mode == 1) v += ldin(dt, src2, (size_t)(r0 + rr) * jb.C + c0 + tx);
        T[rr][tx] = v;
    }
    __syncthreads();
    for (int rr = ty; rr < 32; rr += 8)
        jb.d[(size_t)(c0 + rr) * jb.ldd + jb.kofs + r0 + tx] = f2b(T[tx][rr]);
}

// ============ FUSED MFMA PIPELINE ============
// One block per (batch, row-half). Phase A: pk[128][512] = know^T @ Wk + bk, with the
// A-operand gathered straight from `know` into registers (transpose implicit, no A-LDS),
// prefetched one K-tile ahead. pk lives entirely in LDS. Phase B: h = pk @ W_eff
// (pm folded into B while staging), ReLU * u, row-reduce -> logit. No intermediate
// global traffic, no pkT, no lpart.
__global__ __launch_bounds__(256, 1) void g12_fused(const void* __restrict__ know,
                                                    const bf16* __restrict__ WkT,
                                                    const float* __restrict__ bkf,
                                                    const bf16* __restrict__ Wc1T2,
                                                    const float* __restrict__ pmf,
                                                    const float* __restrict__ t3b,
                                                    const float* __restrict__ uf,
                                                    const float* __restrict__ bias_r,
                                                    float* __restrict__ logit,
                                                    const int* __restrict__ flag){
    extern __shared__ char smem[];
    bf16* pk  = (bf16*)smem;                         // [128][PKP]
    bf16* stg = (bf16*)(smem + 128 * PKP * 2);       // [128][SGP] (Bs in phase A, Ws in phase B)
    const int dt = *flag;
    const int tid = threadIdx.x, lane = tid & 63, wave = tid >> 6;
    const int q = lane >> 4, mr = lane & 15;
    const int bid = blockIdx.x;
    const int u = (bid & 7) * 64 + (bid >> 3);       // same-XCD (b,rt) pairing
    const int b = u >> 1, rt = u & 1;
    const int r0 = rt * 128;
    const int colh = tid >> 1, kbh = (tid & 1) * 32; // staging slice: col 0..127, k-half

    // ---- phase A state ----
    float          frA[2][2][8];                     // fp32 raw gather
    unsigned short urA[2][2][8];                     // bf16 raw gather
    float4 Bv[4];
    s8v af[2][2];
    f4v acc[4][2][8];
    #pragma unroll
    for (int n = 0; n < 4; ++n)
        #pragma unroll
        for (int t = 0; t < 2; ++t)
            #pragma unroll
            for (int j = 0; j < 8; ++j){ f4v z = {0.f,0.f,0.f,0.f}; acc[n][t][j] = z; }

    const int rowA[2] = { r0 + wave * 32 + mr, r0 + wave * 32 + 16 + mr };
    const int rowC[2] = { rowA[0] < HWN ? rowA[0] : HWN - 1,
                          rowA[1] < HWN ? rowA[1] : HWN - 1 };   // clamped (always in-bounds)

    auto issueA = [&](int ks){
        #pragma unroll
        for (int t = 0; t < 2; ++t){
            const size_t base = ((size_t)b * DD + ks * 64 + q * 8) * HWN + rowC[t];
            if (dt == 0){
                const float* kp = (const float*)know;
                #pragma unroll
                for (int h = 0; h < 2; ++h)
                    #pragma unroll
                    for (int e = 0; e < 8; ++e)
                        frA[t][h][e] = kp[base + (size_t)(h * 32 + e) * HWN];
            } else {
                const unsigned short* kp = (const unsigned short*)know;
                #pragma unroll
                for (int h = 0; h < 2; ++h)
                    #pragma unroll
                    for (int e = 0; e < 8; ++e)
                        urA[t][h][e] = kp[base + (size_t)(h * 32 + e) * HWN];
            }
        }
    };
    auto packA = [&](){
        #pragma unroll
        for (int t = 0; t < 2; ++t){
            const bool vld = (rowA[t] < HWN);
            #pragma unroll
            for (int h = 0; h < 2; ++h){
                union { bf16 hh[8]; unsigned short uu[8]; s8v v; } tmp;
                if (dt == 0){
                    #pragma unroll
                    for (int e = 0; e < 8; ++e) tmp.hh[e] = f2b(vld ? frA[t][h][e] : 0.f);
                } else {
                    #pragma unroll
                    for (int e = 0; e < 8; ++e) tmp.uu[e] = vld ? urA[t][h][e] : (unsigned short)0;
                }
                af[t][h] = tmp.v;
            }
        }
    };
    auto issueB = [&](int ks, int n){
        const bf16* wp = WkT + (size_t)(n * 128 + colh) * DD + ks * 64 + kbh;
        #pragma unroll
        for (int t4 = 0; t4 < 4; ++t4) Bv[t4] = *(const float4*)(wp + t4 * 8);
    };
    auto writeB = [&](){
        #pragma unroll
        for (int t4 = 0; t4 < 4; ++t4)
            *(float4*)&stg[colh * SGP + kbh + t4 * 8] = Bv[t4];
    };

    // ---- phase A: 8 K-tiles x 4 col-tiles ----
    issueA(0);
    issueB(0, 0);
    for (int ks = 0; ks < 8; ++ks){
        packA();                       // waits gather issued last K-tile
        if (ks < 7) issueA(ks + 1);    // ~4 sub-steps of slack before use
        #pragma unroll
        for (int n = 0; n < 4; ++n){
            __syncthreads();           // prior sub-step's LDS reads done
            writeB();
            { int ks2 = (n == 3) ? ks + 1 : ks, n2 = (n + 1) & 3;
              if (ks2 > 7){ ks2 = 7; n2 = 3; }
              issueB(ks2, n2); }       // in flight across the MFMA burst
            __syncthreads();           // Bs visible
            #pragma unroll
            for (int h = 0; h < 2; ++h){
                #pragma unroll
                for (int j = 0; j < 8; ++j){
                    s8v bb = *(const s8v*)&stg[(j * 16 + mr) * SGP + h * 32 + q * 8];
                    acc[n][0][j] = __builtin_amdgcn_mfma_f32_16x16x32_bf16(af[0][h], bb, acc[n][0][j], 0, 0, 0);
                    acc[n][1][j] = __builtin_amdgcn_mfma_f32_16x16x32_bf16(af[1][h], bb, acc[n][1][j], 0, 0, 0);
                }
            }
        }
    }

    // ---- phase B state (issue first W slice early, overlap with pk write) ----
    float4 Wv[8], Pv[8];
    auto issueW = [&](int n, int es){
        const bf16*  wrow = Wc1T2 + (size_t)(n * 128 + colh) * (2 * DD) + es * 64 + kbh;
        const float* pmb  = pmf + (size_t)b * DD + es * 64 + kbh;
        #pragma unroll
        for (int t4 = 0; t4 < 4; ++t4){
            Wv[2 * t4]     = *(const float4*)(wrow + t4 * 8);
            Wv[2 * t4 + 1] = *(const float4*)(wrow + DD + t4 * 8);
            Pv[2 * t4]     = *(const float4*)(pmb + t4 * 8);
            Pv[2 * t4 + 1] = *(const float4*)(pmb + t4 * 8 + 4);
        }
    };
    auto writeW = [&](){
        #pragma unroll
        for (int t4 = 0; t4 < 4; ++t4){
            union { bf16 h[8]; float4 f; } w1, w2, be;
            w1.f = Wv[2 * t4]; w2.f = Wv[2 * t4 + 1];
            float4 pA = Pv[2 * t4], pB = Pv[2 * t4 + 1];
            #pragma unroll
            for (int j = 0; j < 4; ++j){
                be.h[j]     = f2b((&pA.x)[j] * b2f(w1.h[j])     + b2f(w2.h[j]));
                be.h[4 + j] = f2b((&pB.x)[j] * b2f(w1.h[4 + j]) + b2f(w2.h[4 + j]));
            }
            *(float4*)&stg[colh * SGP + kbh + t4 * 8] = be.f;
        }
    };
    issueW(0, 0);

    // ---- pk -> LDS (bias folded) ----
    #pragma unroll
    for (int n = 0; n < 4; ++n)
        #pragma unroll
        for (int j = 0; j < 8; ++j){
            const int col = n * 128 + j * 16 + mr;
            const float bv = bkf[col];
            #pragma unroll
            for (int t = 0; t < 2; ++t)
                #pragma unroll
                for (int i = 0; i < 4; ++i)
                    pk[(wave * 32 + t * 16 + q * 4 + i) * PKP + col] = f2b(acc[n][t][j][i] + bv);
        }

    // ---- phase B: 4 col-tiles x 8 e-tiles; epilogue accumulates logits ----
    float part[2][4] = {{0.f,0.f,0.f,0.f},{0.f,0.f,0.f,0.f}};
    for (int n = 0; n < 4; ++n){
        f4v hacc[2][8];
        #pragma unroll
        for (int t = 0; t < 2; ++t)
            #pragma unroll
            for (int j = 0; j < 8; ++j){ f4v z = {0.f,0.f,0.f,0.f}; hacc[t][j] = z; }
        for (int es = 0; es < 8; ++es){
            __syncthreads();           // prior LDS reads done (also fences pk writes once)
            writeW();
            { int n2 = n, e2 = es + 1;
              if (e2 == 8){ e2 = 0; n2 = n + 1; }
              if (n2 == 4){ n2 = 3; e2 = 7; }
              issueW(n2, e2); }
            __syncthreads();           // Ws visible
            #pragma unroll
            for (int h = 0; h < 2; ++h){
                s8v a0 = *(const s8v*)&pk[(wave * 32 + mr) * PKP + es * 64 + h * 32 + q * 8];
                s8v a1 = *(const s8v*)&pk[(wave * 32 + 16 + mr) * PKP + es * 64 + h * 32 + q * 8];
                #pragma unroll
                for (int j = 0; j < 8; ++j){
                    s8v bb = *(const s8v*)&stg[(j * 16 + mr) * SGP + h * 32 + q * 8];
                    hacc[0][j] = __builtin_amdgcn_mfma_f32_16x16x32_bf16(a0, bb, hacc[0][j], 0, 0, 0);
                    hacc[1][j] = __builtin_amdgcn_mfma_f32_16x16x32_bf16(a1, bb, hacc[1][j], 0, 0, 0);
                }
            }
        }
        #pragma unroll
        for (int t = 0; t < 2; ++t)
            #pragma unroll
            for (int j = 0; j < 8; ++j){
                const int col = n * 128 + j * 16 + mr;
                #pragma unroll
                for (int i = 0; i < 4; ++i){
                    const int rl = r0 + wave * 32 + t * 16 + q * 4 + i;
                    if (rl < HWN){
                        float hv = hacc[t][j][i] + t3b[(size_t)b * DD + col];
                        part[t][i] += fmaxf(hv, 0.f) * uf[(size_t)b * DD + col];
                    }
                }
            }
    }
    #pragma unroll
    for (int t = 0; t < 2; ++t)
        #pragma unroll
        for (int i = 0; i < 4; ++i){
            float v = part[t][i];
            v += __shfl_xor(v, 1, 16);
            v += __shfl_xor(v, 2, 16);
            v += __shfl_xor(v, 4, 16);
            v += __shfl_xor(v, 8, 16);
            const int rl = r0 + wave * 32 + t * 16 + q * 4 + i;
            if (mr == 0 && rl < HWN)
                logit[(size_t)b * HWN + rl] = v + bias_r[b];
        }
}

// ---------------- fast small GEMM: LDS-free, one 16x16 MFMA tile per wave ----------------
struct SSeg { const void* A; int a_ws, lda, K, koff; };
struct SP {
    SSeg s[2]; int nseg;
    const bf16* BT; int ldb;       // BT[n][k] bf16
    const float* amul;             // optional per-k multiplier on A (seg 0 only)
    const void* bias;              // raw input dtype, may be null
    float* C; int M, N, act;       // act: 0 none, 1 tanh
    void* out2; int o2off;         // optional extra output (input dtype), at o2off
};
struct SPP { SP j[2]; };

__global__ __launch_bounds__(256) void sgemm_k(SPP P, const int* __restrict__ flag){
    const int dt = *flag;
    const SP p = P.j[blockIdx.z];
    const int tid = threadIdx.x, lane = tid & 63, w = tid >> 6;
    const int q = lane >> 4, mr = lane & 15;
    const int n0 = blockIdx.x * 16, m0 = blockIdx.y * 64 + w * 16;
    f4v acc = {0.f,0.f,0.f,0.f};
    for (int sg = 0; sg < p.nseg; ++sg){
        const SSeg s = p.s[sg];
        const float* amul = (sg == 0) ? p.amul : nullptr;
        #pragma unroll 4
        for (int k0 = 0; k0 < s.K; k0 += 32){
            const int kk = k0 + q * 8;
            union { bf16 h[8]; s8v v; } a;
            if (s.a_ws || dt == 0){
                const float* Af = (const float*)s.A + (size_t)(m0 + mr) * s.lda + kk;
                float4 f0 = *(const float4*)Af;
                float4 f1 = *(const float4*)(Af + 4);
                float f[8] = {f0.x, f0.y, f0.z, f0.w, f1.x, f1.y, f1.z, f1.w};
                if (amul){
                    #pragma unroll
                    for (int j = 0; j < 8; ++j) f[j] *= amul[kk + j];
                }
                #pragma unroll
                for (int j = 0; j < 8; ++j) a.h[j] = f2b(f[j]);
            } else {
                a.v = *(const s8v*)((const bf16*)s.A + (size_t)(m0 + mr) * s.lda + kk);
                if (amul){
                    #pragma unroll
                    for (int j = 0; j < 8; ++j) a.h[j] = f2b(b2f(a.h[j]) * amul[kk + j]);
                }
            }
            s8v b = *(const s8v*)(p.BT + (size_t)(n0 + mr) * p.ldb + s.koff + kk);
            acc = __builtin_amdgcn_mfma_f32_16x16x32_bf16(a.v, b, acc, 0, 0, 0);
        }
    }
    #pragma unroll
    for (int i = 0; i < 4; ++i){
        int row = m0 + q * 4 + i, col = n0 + mr;
        float v = acc[i] + (p.bias ? ldin(dt, p.bias, col) : 0.f);
        if (p.act == 1) v = tanhf(v);
        p.C[(size_t)row * p.N + col] = v;
        if (p.out2){
            size_t oi = (size_t)p.o2off + (size_t)row * p.N + col;
            if (dt) ((bf16*)p.out2)[oi] = f2b(v);
            else    ((float*)p.out2)[oi] = v;
        }
    }
}

// ---------------- control attention (+ fused bias_r, + fused d_out write) ----------------
__global__ __launch_bounds__(256) void attn_control_k(const float* __restrict__ cq,
                                                      const void* __restrict__ wac,
                                                      const void* __restrict__ bac,
                                                      const void* __restrict__ words,
                                                      float* __restrict__ control,
                                                      const void* __restrict__ bc2,
                                                      const float* __restrict__ warf,
                                                      const void* __restrict__ bar,
                                                      float* __restrict__ bias_r,
                                                      void* __restrict__ out,
                                                      const int* __restrict__ flag){
    const int dt = *flag;
    const int b = blockIdx.x, tid = threadIdx.x;
    __shared__ float cw[DD];
    __shared__ float lg[SS];
    __shared__ float es[SS];
    __shared__ float red[256];
    for (int d = tid; d < DD; d += 256) cw[d] = cq[(size_t)b*DD + d] * ldin(dt, wac, d);
    __syncthreads();
    int s = tid >> 3, l8 = tid & 7;
    float p = 0.f;
    for (int d = l8; d < DD; d += 8) p += cw[d] * ldin(dt, words, ((size_t)b*SS + s)*DD + d);
    for (int off = 4; off; off >>= 1) p += __shfl_down(p, off, 8);
    if (l8 == 0) lg[s] = p + ldin(dt, bac, 0);
    __syncthreads();
    if (tid == 0){
        float mx = -INFINITY;
        for (int i = 0; i < SS; ++i) mx = fmaxf(mx, lg[i]);
        float sm = 0.f;
        for (int i = 0; i < SS; ++i){ es[i] = expf(lg[i] - mx); sm += es[i]; }
        float inv = 1.f / sm;
        for (int i = 0; i < SS; ++i) es[i] *= inv;
    }
    __syncthreads();
    float vb = 0.f;
    for (int d = tid; d < DD; d += 256){
        float c = 0.f;
        #pragma unroll 8
        for (int s2 = 0; s2 < SS; ++s2) c += es[s2] * ldin(dt, words, ((size_t)b*SS + s2)*DD + d);
        control[(size_t)b*DD + d] = c;
        if (dt) ((bf16*)out)[(size_t)b*DD + d] = f2b(c);
        else    ((float*)out)[(size_t)b*DD + d] = c;
        vb += ldin(dt, bc2, d) * c * warf[d];
    }
    red[tid] = vb; __syncthreads();
    for (int off = 128; off; off >>= 1){ if (tid < off) red[tid] += red[tid + off]; __syncthreads(); }
    if (tid == 0) bias_r[b] = red[0] + ldin(dt, bar, 0);
}

// ---------------- softmax over HW + read ----------------
__global__ __launch_bounds__(256) void softmax_read_k(const float* __restrict__ logit,
                                                      const void* __restrict__ know,
                                                      float* __restrict__ readout,
                                                      const int* __restrict__ flag){
    const int dt = *flag;
    const int b = blockIdx.x, tid = threadIdx.x;
    __shared__ float a[HWN];
    __shared__ float red[256];
    float x = (tid < HWN) ? logit[(size_t)b*HWN + tid] : -INFINITY;
    red[tid] = x; __syncthreads();
    for (int off = 128; off; off >>= 1){ if (tid < off) red[tid] = fmaxf(red[tid], red[tid + off]); __syncthreads(); }
    float mx = red[0]; __syncthreads();
    float e = (tid < HWN) ? expf(x - mx) : 0.f;
    red[tid] = e; __syncthreads();
    for (int off = 128; off; off >>= 1){ if (tid < off) red[tid] += red[tid + off]; __syncthreads(); }
    float inv = 1.f / red[0];
    if (tid < HWN) a[tid] = e * inv;
    __syncthreads();
    for (int d = tid; d < DD; d += 256){
        size_t base = ((size_t)b*DD + d) * HWN;
        float sum = 0.f;
        if (dt){
            const ushort4* k4 = (const ushort4*)((const unsigned short*)know + base);
            #pragma unroll 7
            for (int c = 0; c < HWN/4; ++c){
                ushort4 u4 = k4[c];
                sum += a[4*c+0]*us2f(u4.x) + a[4*c+1]*us2f(u4.y)
                     + a[4*c+2]*us2f(u4.z) + a[4*c+3]*us2f(u4.w);
            }
        } else {
            const float4* k4 = (const float4*)((const float*)know + base);
            #pragma unroll 7
            for (int c = 0; c < HWN/4; ++c){
                float4 f4 = k4[c];
                sum += a[4*c+0]*f4.x + a[4*c+1]*f4.y + a[4*c+2]*f4.z + a[4*c+3]*f4.w;
            }
        }
        readout[(size_t)b*DD + d] = sum;
    }
}

extern "C" void kernel_launch(void* const* d_in, const int* in_sizes, int n_in,
                              void* d_out, int out_size, void* d_ws, size_t ws_size,
                              hipStream_t stream){
    const void* words    = d_in[0];
    const void* question = d_in[1];
    const void* know     = d_in[2];
    const void* control0 = d_in[3];
    const void* memory0  = d_in[4];
    const void* Wsc = d_in[5];   const void* bsc = d_in[6];
    const void* Wp  = d_in[7];   const void* bp  = d_in[8];
    const void* Wcq = d_in[9];   const void* bcq = d_in[10];
    const void* wac = d_in[11];  const void* bac = d_in[12];
    const void* Wm  = d_in[13];  const void* bm  = d_in[14];
    const void* Wk  = d_in[15];  const void* bk  = d_in[16];
    const void* Wc1 = d_in[17];  const void* bc1 = d_in[18];
    const void* Wc2 = d_in[19];  const void* bc2 = d_in[20];
    const void* war = d_in[21];  const void* bar = d_in[22];
    // d_in[23..26] dead: softmax over singleton axis == 1 => attn_mem == memory0
    const void* Wwcat = d_in[27]; const void* bwcat = d_in[28];

    int* flag = (int*)d_ws;
    float* F = ((float*)d_ws) + 16;
    const int NBD = BB * DD;
    float* q_   = F;
    float* pa   = F + 1*NBD;
    float* cq   = F + 2*NBD;
    float* ctrl = F + 3*NBD;
    float* pm   = F + 4*NBD;
    float* t3b  = F + 5*NBD;
    float* u_   = F + 6*NBD;
    float* rd   = F + 7*NBD;
    float* nm   = F + 8*NBD;
    float* bias_r = F + 9*NBD;                  // [B]
    float* warf   = bias_r + BB;                // [D]
    float* bkf    = warf + DD;                  // [D]
    float* logit  = bkf + DD;                   // [B*HW]
    size_t off_f = 16 + 9*(size_t)NBD + BB + 2*DD + (size_t)BB*HWN;
    size_t byte_off = (off_f * 4 + 255) & ~(size_t)255;
    bf16* WB = (bf16*)((char*)d_ws + byte_off);
    bf16* WscT   = WB;                          // [512][1024]
    bf16* WcqT   = WscT  + (size_t)DD*2*DD;     // [512][1024]
    bf16* Wc1T2  = WcqT  + (size_t)DD*2*DD;     // [512][1024]
    bf16* WwcatF = Wc1T2 + (size_t)DD*2*DD;     // [512][1024]
    bf16* WpT    = WwcatF+ (size_t)DD*2*DD;     // [512][512]
    bf16* WmT    = WpT   + (size_t)DD*DD;
    bf16* Wc1t3T = WmT   + (size_t)DD*DD;
    bf16* WkT    = Wc1t3T+ (size_t)DD*DD;
    bf16* Wc2cv  = WkT   + (size_t)DD*DD;

    dim3 blk(256);

    detect_k<<<dim3(1), blk, 0, stream>>>(question, flag);

    // ---- fused weight prep (single launch, runtime dt) ----
    {
        PrepP P; int bo = 0;
        auto J = [&](const void* s, const void* sb, const void* s2, const void* s2b,
                     bf16* d, int R, int C, int ldd, int kofs, int mode, int idx){
            int nb = (mode == 3) ? 1 : ((R >> 5) * (C >> 5));
            P.j[idx] = PJob{ s, sb, s2, s2b, d, R, C, ldd, kofs, mode, bo };
            bo += nb;
        };
        const void* Wc1t3_f = (const void*)((const float*)Wc1 + (size_t)2*DD*DD);
        const void* Wc1t3_b = (const void*)((const bf16*) Wc1 + (size_t)2*DD*DD);
        const void* Ww1_f = (const void*)((const float*)Wwcat + (size_t)DD*DD);
        const void* Ww1_b = (const void*)((const bf16*) Wwcat + (size_t)DD*DD);
        const void* Ww2_f = (const void*)((const float*)Wwcat + (size_t)2*DD*DD);
        const void* Ww2_b = (const void*)((const bf16*) Wwcat + (size_t)2*DD*DD);
        J(Wsc,   Wsc,   nullptr, nullptr, WscT,   2*DD, DD, 2*DD, 0,   0, 0);
        J(Wp,    Wp,    nullptr, nullptr, WpT,    DD,   DD, DD,   0,   0, 1);
        J(Wcq,   Wcq,   nullptr, nullptr, WcqT,   2*DD, DD, 2*DD, 0,   0, 2);
        J(Wm,    Wm,    nullptr, nullptr, WmT,    DD,   DD, DD,   0,   0, 3);
        J(Wc1,   Wc1,   nullptr, nullptr, Wc1T2,  2*DD, DD, 2*DD, 0,   0, 4);
        J(Wc1t3_f, Wc1t3_b, nullptr, nullptr, Wc1t3T, DD, DD, DD, 0,   0, 5);
        J(Wk,    Wk,    nullptr, nullptr, WkT,    DD,   DD, DD,   0,   0, 6);
        J(Wwcat, Wwcat, nullptr, nullptr, WwcatF, DD,   DD, 2*DD, 0,   0, 7);
        J(Ww1_f, Ww1_b, Ww2_f,   Ww2_b,   WwcatF, DD,   DD, 2*DD, 512, 1, 8);
        J(Wc2,   Wc2,   nullptr, nullptr, Wc2cv,  DD,   DD, DD,   0,   2, 9);
        J(nullptr,nullptr,nullptr,nullptr,nullptr,0,    0,  0,    0,   3, 10);
        P.war = war; P.bk = bk; P.warf = warf; P.bkf = bkf;
        prep_k<<<dim3(bo), blk, 0, stream>>>(P, flag);
    }

    SPP P2;
    auto mkjob = [&](SP& p){ p = SP{}; };

    // launch 1: q = tanh(question @ Wsc + bsc)  ||  pm = memory0 @ Wm + bm
    mkjob(P2.j[0]);
    P2.j[0].nseg = 1;
    P2.j[0].s[0] = SSeg{ question, 0, 2*DD, 2*DD, 0 };
    P2.j[0].BT = WscT; P2.j[0].ldb = 2*DD;
    P2.j[0].bias = bsc; P2.j[0].C = q_; P2.j[0].M = BB; P2.j[0].N = DD; P2.j[0].act = 1;
    mkjob(P2.j[1]);
    P2.j[1].nseg = 1;
    P2.j[1].s[0] = SSeg{ memory0, 0, DD, DD, 0 };
    P2.j[1].BT = WmT; P2.j[1].ldb = DD;
    P2.j[1].bias = bm; P2.j[1].C = pm; P2.j[1].M = BB; P2.j[1].N = DD; P2.j[1].act = 0;
    sgemm_k<<<dim3(DD/16, BB/64, 2), blk, 0, stream>>>(P2, flag);

    // launch 2: pa = q @ Wp + bp  ||  t3b = pm @ Wc1[2D:3D] + bc1
    mkjob(P2.j[0]);
    P2.j[0].nseg = 1;
    P2.j[0].s[0] = SSeg{ q_, 1, DD, DD, 0 };
    P2.j[0].BT = WpT; P2.j[0].ldb = DD;
    P2.j[0].bias = bp; P2.j[0].C = pa; P2.j[0].M = BB; P2.j[0].N = DD; P2.j[0].act = 0;
    mkjob(P2.j[1]);
    P2.j[1].nseg = 1;
    P2.j[1].s[0] = SSeg{ pm, 1, DD, DD, 0 };
    P2.j[1].BT = Wc1t3T; P2.j[1].ldb = DD;
    P2.j[1].bias = bc1; P2.j[1].C = t3b; P2.j[1].M = BB; P2.j[1].N = DD; P2.j[1].act = 0;
    sgemm_k<<<dim3(DD/16, BB/64, 2), blk, 0, stream>>>(P2, flag);

    // launch 3: cq = [control0, pa] @ Wcq + bcq
    mkjob(P2.j[0]);
    P2.j[0].nseg = 2;
    P2.j[0].s[0] = SSeg{ control0, 0, DD, DD, 0 };
    P2.j[0].s[1] = SSeg{ pa,       1, DD, DD, 512 };
    P2.j[0].BT = WcqT; P2.j[0].ldb = 2*DD;
    P2.j[0].bias = bcq; P2.j[0].C = cq; P2.j[0].M = BB; P2.j[0].N = DD; P2.j[0].act = 0;
    sgemm_k<<<dim3(DD/16, BB/64, 1), blk, 0, stream>>>(P2, flag);

    // control (+ fused bias_r, + writes first half of d_out)
    attn_control_k<<<dim3(BB), blk, 0, stream>>>(cq, wac, bac, words, ctrl,
                                                 bc2, warf, bar, bias_r, d_out, flag);

    // u[b,e] = sum_d Wc2[e,d] * (ctrl[b,d]*war[d])
    mkjob(P2.j[0]);
    P2.j[0].nseg = 1;
    P2.j[0].s[0] = SSeg{ ctrl, 1, DD, DD, 0 };
    P2.j[0].BT = Wc2cv; P2.j[0].ldb = DD; P2.j[0].amul = warf;
    P2.j[0].C = u_; P2.j[0].M = BB; P2.j[0].N = DD; P2.j[0].act = 0;
    sgemm_k<<<dim3(DD/16, BB/64, 1), blk, 0, stream>>>(P2, flag);

    // fused know-transpose + GEMM1 + GEMM2 + ReLU-dot epilogue -> logit
    {
        static bool attr_set = false;
        const int g12_lds = 128 * PKP * 2 + 128 * SGP * 2;   // 151,552 B <= 160 KiB
        if (!attr_set){
            (void)hipFuncSetAttribute(reinterpret_cast<const void*>(g12_fused),
                                      hipFuncAttributeMaxDynamicSharedMemorySize, g12_lds);
            attr_set = true;
        }
        g12_fused<<<dim3(2 * BB), blk, g12_lds, stream>>>(know, WkT, bkf, Wc1T2,
                                                          pm, t3b, u_, bias_r, logit, flag);
    }

    // softmax + read
    softmax_read_k<<<dim3(BB), blk, 0, stream>>>(logit, know, rd, flag);

    // next_mem = [rd, memory0] @ WwcatF^T + bwcat  (writes second half of d_out directly)
    mkjob(P2.j[0]);
    P2.j[0].nseg = 2;
    P2.j[0].s[0] = SSeg{ rd,      1, DD, DD, 0 };
    P2.j[0].s[1] = SSeg{ memory0, 0, DD, DD, 512 };
    P2.j[0].BT = WwcatF; P2.j[0].ldb = 2*DD;
    P2.j[0].bias = bwcat; P2.j[0].C = nm; P2.j[0].M = BB; P2.j[0].N = DD; P2.j[0].act = 0;
    P2.j[0].out2 = d_out; P2.j[0].o2off = NBD;
    sgemm_k<<<dim3(DD/16, BB/64, 1), blk, 0, stream>>>(P2, flag);
}

// Round 4
// 607.407 us; speedup vs baseline: 1.4408x; 1.4408x over previous
//
#include <hip/hip_runtime.h>
#include <hip/hip_bf16.h>
#include <math.h>

typedef __hip_bfloat16 bf16;
typedef __attribute__((ext_vector_type(8))) short s8v;   // 8 bf16 = 4 VGPR (MFMA A/B frag)
typedef __attribute__((ext_vector_type(4))) short s4v;   // 4 bf16 = 8B
typedef __attribute__((ext_vector_type(4))) float f4v;   // MFMA C/D frag

// B=256, S=32, D=512, HW=196
#define BB 256
#define SS 32
#define DD 512
#define HWN 196

__device__ __forceinline__ float b2f(bf16 x){ return __bfloat162float(x); }
__device__ __forceinline__ bf16 f2b(float x){ return __float2bfloat16(x); }
__device__ __forceinline__ float us2f(unsigned short u){
    union { unsigned int i; float f; } t; t.i = ((unsigned int)u) << 16; return t.f;
}
// dt: 1 = inputs are bf16, 0 = inputs are fp32 (runtime-uniform)
__device__ __forceinline__ float ldin(int dt, const void* p, size_t i){
    return dt ? b2f(((const bf16*)p)[i]) : ((const float*)p)[i];
}
// async global->LDS, 16B per lane; LDS dest is wave-uniform base + lane*16
__device__ __forceinline__ void g2l16(void* lds, const void* gsrc){
    __builtin_amdgcn_global_load_lds(
        (const __attribute__((address_space(1))) unsigned int*)gsrc,
        (__attribute__((address_space(3))) unsigned int*)lds, 16, 0, 0);
}

// ---------------- dtype detector ----------------
__global__ void detect_k(const void* q, int* flag){
    __shared__ int cnt;
    if (threadIdx.x == 0) cnt = 0;
    __syncthreads();
    const unsigned short* u = (const unsigned short*)q;
    unsigned short v = u[threadIdx.x * 4];
    int e = (v >> 7) & 0xFF;
    atomicAdd(&cnt, (e >= 100 && e <= 140) ? 1 : 0);
    __syncthreads();
    if (threadIdx.x == 0) *flag = (cnt > 128) ? 1 : 0;
}

// ---------------- fused weight prep (runtime dt; per-dtype alt pointers) ----------------
struct PJob { const void* s; const void* s_b; const void* s2; const void* s2_b;
              bf16* d; int R, C, ldd, kofs, mode, boff; };
struct PrepP { PJob j[11]; const void* war; const void* bk; float* warf; float* bkf; };

__global__ __launch_bounds__(256) void prep_k(PrepP P, const int* __restrict__ flag){
    const int dt = *flag;
    __shared__ float T[32][33];
    int bx = blockIdx.x;
    int ji = 0;
    #pragma unroll
    for (int i = 0; i < 11; ++i) if (bx >= P.j[i].boff) ji = i;
    PJob jb = P.j[ji];
    const void* src  = dt ? jb.s_b  : jb.s;
    const void* src2 = dt ? jb.s2_b : jb.s2;
    int t = bx - jb.boff;
    int tx = threadIdx.x & 31, ty = threadIdx.x >> 5;
    if (jb.mode == 3){
        for (int i = threadIdx.x; i < DD; i += 256){
            P.warf[i] = ldin(dt, P.war, i);
            P.bkf[i]  = ldin(dt, P.bk, i);
        }
        return;
    }
    int nrt = jb.R >> 5;
    int r0 = (t % nrt) << 5, c0 = (t / nrt) << 5;
    if (jb.mode == 2){
        for (int rr = ty; rr < 32; rr += 8)
            jb.d[(size_t)(r0 + rr) * jb.ldd + jb.kofs + c0 + tx] =
                f2b(ldin(dt, src, (size_t)(r0 + rr) * jb.C + c0 + tx));
        return;
    }
    for (int rr = ty; rr < 32; rr += 8){
        float v = ldin(dt, src, (size_t)(r0 + rr) * jb.C + c0 + tx);
        if (jb.mode == 1) v += ldin(dt, src2, (size_t)(r0 + rr) * jb.C + c0 + tx);
        T[rr][tx] = v;
    }
    __syncthreads();
    for (int rr = ty; rr < 32; rr += 8)
        jb.d[(size_t)(c0 + rr) * jb.ldd + jb.kofs + r0 + tx] = f2b(T[tx][rr]);
}

// swizzled byte offset within a [rows][64] bf16 tile (128B rows, 16B slots):
// logical (row, slot) -> physical slot = slot ^ (row&7)  => b128 reads 2-way (free)
__device__ __forceinline__ int swzo(int row, int slot){
    return row * 128 + ((slot ^ (row & 7)) << 4);
}

// ---------------- MFMA GEMM 1: A2[M][1024] = [pk*pm | pk], pk = know^T @ Wk + bk ----
// 128x128 C-tile, BK=64, double-buffered LDS, ONE barrier per K-step.
// A: reg-gathered (transpose) from know, issued early, ds_written after MFMA burst.
// B: global_load_lds 16B, source slot pre-swizzled.
__global__ __launch_bounds__(256) void g1_mfma(const void* __restrict__ know,
                                               const bf16* __restrict__ BT,
                                               const float* __restrict__ bkf,
                                               const float* __restrict__ pmf,
                                               bf16* __restrict__ A2,
                                               int b0, int swz,
                                               const int* __restrict__ flag){
    const int dt = *flag;
    __shared__ __align__(16) char lA[2][128 * 128];
    __shared__ __align__(16) char lB[2][128 * 128];
    const int tid = threadIdx.x, lane = tid & 63, wave = tid >> 6;
    const int q = lane >> 4, mr = lane & 15;
    int idb = blockIdx.x, rt, ct;
    if (swz){ int g = idb >> 5, w = idb & 31; rt = g * 8 + (w & 7); ct = w >> 3; }
    else    { rt = idb >> 2; ct = idb & 3; }
    const int r0 = rt * 128, c0 = ct * 128;
    // A transpose-gather constants (4|196: aligned n-quad never crosses a batch)
    const int quad = tid >> 3;            // 0..31 : 4-row (M/n) group
    const int kg   = tid & 7;             // 0..7  : 4-k group within a 32-k half
    const int m    = r0 + quad * 4;
    const int bl   = m / HWN;
    const int n    = m - bl * HWN;
    const size_t abase = ((size_t)(b0 + bl) * DD) * HWN + n;

    float4  fr[2][4];
    ushort4 ur[2][4];
    f4v acc[2][8];
    #pragma unroll
    for (int t = 0; t < 2; ++t)
        #pragma unroll
        for (int j = 0; j < 8; ++j){ f4v z = {0.f,0.f,0.f,0.f}; acc[t][j] = z; }

    auto issueA = [&](int t){
        #pragma unroll
        for (int h = 0; h < 2; ++h){
            const int kb = t * 64 + h * 32 + kg * 4;
            if (dt == 0){
                const float* kp = (const float*)know + abase + (size_t)kb * HWN;
                fr[h][0] = *(const float4*)kp;
                fr[h][1] = *(const float4*)(kp + HWN);
                fr[h][2] = *(const float4*)(kp + 2 * HWN);
                fr[h][3] = *(const float4*)(kp + 3 * HWN);
            } else {
                const unsigned short* kp = (const unsigned short*)know + abase + (size_t)kb * HWN;
                ur[h][0] = *(const ushort4*)kp;
                ur[h][1] = *(const ushort4*)(kp + HWN);
                ur[h][2] = *(const ushort4*)(kp + 2 * HWN);
                ur[h][3] = *(const ushort4*)(kp + 3 * HWN);
            }
        }
    };
    auto writeA = [&](int buf){
        #pragma unroll
        for (int h = 0; h < 2; ++h){
            union { bf16 hh[4]; unsigned short uu[4]; s4v v; } col[4];
            if (dt == 0){
                #pragma unroll
                for (int j = 0; j < 4; ++j){
                    col[j].hh[0] = f2b((&fr[h][0].x)[j]);
                    col[j].hh[1] = f2b((&fr[h][1].x)[j]);
                    col[j].hh[2] = f2b((&fr[h][2].x)[j]);
                    col[j].hh[3] = f2b((&fr[h][3].x)[j]);
                }
            } else {
                #pragma unroll
                for (int j = 0; j < 4; ++j){
                    col[j].uu[0] = (&ur[h][0].x)[j];
                    col[j].uu[1] = (&ur[h][1].x)[j];
                    col[j].uu[2] = (&ur[h][2].x)[j];
                    col[j].uu[3] = (&ur[h][3].x)[j];
                }
            }
            const int slot = h * 4 + (kg >> 1);
            const int sub  = (kg & 1) << 3;
            #pragma unroll
            for (int j = 0; j < 4; ++j){
                const int row = quad * 4 + j;
                *(s4v*)&lA[buf][row * 128 + (((slot ^ (row & 7))) << 4) + sub] = col[j].v;
            }
        }
    };
    auto stageB = [&](int t, int buf){
        #pragma unroll
        for (int c = 0; c < 4; ++c){
            const int r0c = (c * 4 + wave) * 8;
            const int row = r0c + (lane >> 3);
            const int ls  = (lane & 7) ^ (row & 7);
            g2l16(&lB[buf][r0c * 128], BT + (size_t)(c0 + row) * DD + t * 64 + ls * 8);
        }
    };
    auto mfmaStep = [&](int buf){
        #pragma unroll
        for (int h = 0; h < 2; ++h){
            const int slot = h * 4 + q;
            const int ra0 = wave * 32 + mr, ra1 = ra0 + 16;
            s8v a0 = *(const s8v*)&lA[buf][swzo(ra0, slot)];
            s8v a1 = *(const s8v*)&lA[buf][swzo(ra1, slot)];
            #pragma unroll
            for (int j = 0; j < 8; ++j){
                const int rb = j * 16 + mr;
                s8v bb = *(const s8v*)&lB[buf][swzo(rb, slot)];
                acc[0][j] = __builtin_amdgcn_mfma_f32_16x16x32_bf16(a0, bb, acc[0][j], 0, 0, 0);
                acc[1][j] = __builtin_amdgcn_mfma_f32_16x16x32_bf16(a1, bb, acc[1][j], 0, 0, 0);
            }
        }
    };

    issueA(0); stageB(0, 0);
    writeA(0);
    __syncthreads();
    int cur = 0;
    for (int t = 0; t < 8; ++t){
        if (t < 7){ stageB(t + 1, cur ^ 1); issueA(t + 1); }
        mfmaStep(cur);
        if (t < 7) writeA(cur ^ 1);
        __syncthreads();
        cur ^= 1;
    }

    // epilogue: A2[row][col] = (pk+bk)*pm ; A2[row][512+col] = pk+bk
    #pragma unroll
    for (int tt = 0; tt < 2; ++tt)
        #pragma unroll
        for (int j = 0; j < 8; ++j){
            const int col = c0 + j * 16 + mr;
            const float bv = bkf[col];
            #pragma unroll
            for (int i = 0; i < 4; ++i){
                const int row = r0 + wave * 32 + tt * 16 + q * 4 + i;
                const int blr = row / HWN;
                const float v = acc[tt][j][i] + bv;
                const float pmv = pmf[(size_t)(b0 + blr) * DD + col];
                A2[(size_t)row * 1024 + col]       = f2b(v * pmv);
                A2[(size_t)row * 1024 + 512 + col] = f2b(v);
            }
        }
}

// ---------------- MFMA GEMM 2: pure bf16 GEMM, K=1024 ----------------
// h = A2 @ Wc1T2^T (+t3b), ReLU * u, row-reduce -> lpart[ct]. Both operands via
// global_load_lds + swizzle; double-buffered; one barrier per K-step.
__global__ __launch_bounds__(256) void g2_mfma(const bf16* __restrict__ A2,
                                               const bf16* __restrict__ BT,
                                               const float* __restrict__ t3b,
                                               const float* __restrict__ uf,
                                               float* __restrict__ lpart,
                                               int b0, int swz){
    __shared__ __align__(16) char lA[2][128 * 128];
    __shared__ __align__(16) char lB[2][128 * 128];
    const int tid = threadIdx.x, lane = tid & 63, wave = tid >> 6;
    const int q = lane >> 4, mr = lane & 15;
    int idb = blockIdx.x, rt, ct;
    if (swz){ int g = idb >> 5, w = idb & 31; rt = g * 8 + (w & 7); ct = w >> 3; }
    else    { rt = idb >> 2; ct = idb & 3; }
    const int r0 = rt * 128, c0 = ct * 128;
    f4v acc[2][8];
    #pragma unroll
    for (int t = 0; t < 2; ++t)
        #pragma unroll
        for (int j = 0; j < 8; ++j){ f4v z = {0.f,0.f,0.f,0.f}; acc[t][j] = z; }

    auto stageA = [&](int t, int buf){
        #pragma unroll
        for (int c = 0; c < 4; ++c){
            const int r0c = (c * 4 + wave) * 8;
            const int row = r0c + (lane >> 3);
            const int ls  = (lane & 7) ^ (row & 7);
            g2l16(&lA[buf][r0c * 128], A2 + (size_t)(r0 + row) * 1024 + t * 64 + ls * 8);
        }
    };
    auto stageB = [&](int t, int buf){
        #pragma unroll
        for (int c = 0; c < 4; ++c){
            const int r0c = (c * 4 + wave) * 8;
            const int row = r0c + (lane >> 3);
            const int ls  = (lane & 7) ^ (row & 7);
            g2l16(&lB[buf][r0c * 128], BT + (size_t)(c0 + row) * 1024 + t * 64 + ls * 8);
        }
    };
    auto mfmaStep = [&](int buf){
        #pragma unroll
        for (int h = 0; h < 2; ++h){
            const int slot = h * 4 + q;
            const int ra0 = wave * 32 + mr, ra1 = ra0 + 16;
            s8v a0 = *(const s8v*)&lA[buf][swzo(ra0, slot)];
            s8v a1 = *(const s8v*)&lA[buf][swzo(ra1, slot)];
            #pragma unroll
            for (int j = 0; j < 8; ++j){
                const int rb = j * 16 + mr;
                s8v bb = *(const s8v*)&lB[buf][swzo(rb, slot)];
                acc[0][j] = __builtin_amdgcn_mfma_f32_16x16x32_bf16(a0, bb, acc[0][j], 0, 0, 0);
                acc[1][j] = __builtin_amdgcn_mfma_f32_16x16x32_bf16(a1, bb, acc[1][j], 0, 0, 0);
            }
        }
    };

    stageA(0, 0); stageB(0, 0);
    __syncthreads();
    int cur = 0;
    for (int t = 0; t < 16; ++t){
        if (t < 15){ stageA(t + 1, cur ^ 1); stageB(t + 1, cur ^ 1); }
        mfmaStep(cur);
        __syncthreads();
        cur ^= 1;
    }

    // epilogue: relu-dot, deterministic per-ct partials
    float part[2][4] = {{0.f,0.f,0.f,0.f},{0.f,0.f,0.f,0.f}};
    #pragma unroll
    for (int tt = 0; tt < 2; ++tt)
        #pragma unroll
        for (int j = 0; j < 8; ++j){
            const int col = c0 + j * 16 + mr;
            #pragma unroll
            for (int i = 0; i < 4; ++i){
                const int row = r0 + wave * 32 + tt * 16 + q * 4 + i;
                const int blr = row / HWN;
                const int b = b0 + blr;
                const float hv = acc[tt][j][i] + t3b[(size_t)b * DD + col];
                part[tt][i] += fmaxf(hv, 0.f) * uf[(size_t)b * DD + col];
            }
        }
    #pragma unroll
    for (int tt = 0; tt < 2; ++tt)
        #pragma unroll
        for (int i = 0; i < 4; ++i){
            float v = part[tt][i];
            v += __shfl_xor(v, 1, 16);
            v += __shfl_xor(v, 2, 16);
            v += __shfl_xor(v, 4, 16);
            v += __shfl_xor(v, 8, 16);
            const int row = r0 + wave * 32 + tt * 16 + q * 4 + i;
            const int blr = row / HWN, rl = row - blr * HWN;
            if (mr == 0)
                lpart[(size_t)ct * (BB * HWN) + (size_t)(b0 + blr) * HWN + rl] = v;
        }
}

// ---------------- fast small GEMM: LDS-free, one 16x16 MFMA tile per wave ----------------
struct SSeg { const void* A; int a_ws, lda, K, koff; };
struct SP {
    SSeg s[2]; int nseg;
    const bf16* BT; int ldb;       // BT[n][k] bf16
    const float* amul;             // optional per-k multiplier on A (seg 0 only)
    const void* bias;              // raw input dtype, may be null
    float* C; int M, N, act;       // act: 0 none, 1 tanh
    void* out2; int o2off;         // optional extra output (input dtype), at o2off
};
struct SPP { SP j[2]; };

__global__ __launch_bounds__(256) void sgemm_k(SPP P, const int* __restrict__ flag){
    const int dt = *flag;
    const SP p = P.j[blockIdx.z];
    const int tid = threadIdx.x, lane = tid & 63, w = tid >> 6;
    const int q = lane >> 4, mr = lane & 15;
    const int n0 = blockIdx.x * 16, m0 = blockIdx.y * 64 + w * 16;
    f4v acc = {0.f,0.f,0.f,0.f};
    for (int sg = 0; sg < p.nseg; ++sg){
        const SSeg s = p.s[sg];
        const float* amul = (sg == 0) ? p.amul : nullptr;
        #pragma unroll 4
        for (int k0 = 0; k0 < s.K; k0 += 32){
            const int kk = k0 + q * 8;
            union { bf16 h[8]; s8v v; } a;
            if (s.a_ws || dt == 0){
                const float* Af = (const float*)s.A + (size_t)(m0 + mr) * s.lda + kk;
                float4 f0 = *(const float4*)Af;
                float4 f1 = *(const float4*)(Af + 4);
                float f[8] = {f0.x, f0.y, f0.z, f0.w, f1.x, f1.y, f1.z, f1.w};
                if (amul){
                    #pragma unroll
                    for (int j = 0; j < 8; ++j) f[j] *= amul[kk + j];
                }
                #pragma unroll
                for (int j = 0; j < 8; ++j) a.h[j] = f2b(f[j]);
            } else {
                a.v = *(const s8v*)((const bf16*)s.A + (size_t)(m0 + mr) * s.lda + kk);
                if (amul){
                    #pragma unroll
                    for (int j = 0; j < 8; ++j) a.h[j] = f2b(b2f(a.h[j]) * amul[kk + j]);
                }
            }
            s8v b = *(const s8v*)(p.BT + (size_t)(n0 + mr) * p.ldb + s.koff + kk);
            acc = __builtin_amdgcn_mfma_f32_16x16x32_bf16(a.v, b, acc, 0, 0, 0);
        }
    }
    #pragma unroll
    for (int i = 0; i < 4; ++i){
        int row = m0 + q * 4 + i, col = n0 + mr;
        float v = acc[i] + (p.bias ? ldin(dt, p.bias, col) : 0.f);
        if (p.act == 1) v = tanhf(v);
        p.C[(size_t)row * p.N + col] = v;
        if (p.out2){
            size_t oi = (size_t)p.o2off + (size_t)row * p.N + col;
            if (dt) ((bf16*)p.out2)[oi] = f2b(v);
            else    ((float*)p.out2)[oi] = v;
        }
    }
}

// ---------------- control attention (+ fused bias_r, + fused d_out write) ----------------
__global__ __launch_bounds__(256) void attn_control_k(const float* __restrict__ cq,
                                                      const void* __restrict__ wac,
                                                      const void* __restrict__ bac,
                                                      const void* __restrict__ words,
                                                      float* __restrict__ control,
                                                      const void* __restrict__ bc2,
                                                      const float* __restrict__ warf,
                                                      const void* __restrict__ bar,
                                                      float* __restrict__ bias_r,
                                                      void* __restrict__ out,
                                                      const int* __restrict__ flag){
    const int dt = *flag;
    const int b = blockIdx.x, tid = threadIdx.x;
    __shared__ float cw[DD];
    __shared__ float lg[SS];
    __shared__ float es[SS];
    __shared__ float red[256];
    for (int d = tid; d < DD; d += 256) cw[d] = cq[(size_t)b*DD + d] * ldin(dt, wac, d);
    __syncthreads();
    int s = tid >> 3, l8 = tid & 7;
    float p = 0.f;
    for (int d = l8; d < DD; d += 8) p += cw[d] * ldin(dt, words, ((size_t)b*SS + s)*DD + d);
    for (int off = 4; off; off >>= 1) p += __shfl_down(p, off, 8);
    if (l8 == 0) lg[s] = p + ldin(dt, bac, 0);
    __syncthreads();
    if (tid == 0){
        float mx = -INFINITY;
        for (int i = 0; i < SS; ++i) mx = fmaxf(mx, lg[i]);
        float sm = 0.f;
        for (int i = 0; i < SS; ++i){ es[i] = expf(lg[i] - mx); sm += es[i]; }
        float inv = 1.f / sm;
        for (int i = 0; i < SS; ++i) es[i] *= inv;
    }
    __syncthreads();
    float vb = 0.f;
    for (int d = tid; d < DD; d += 256){
        float c = 0.f;
        #pragma unroll 8
        for (int s2 = 0; s2 < SS; ++s2) c += es[s2] * ldin(dt, words, ((size_t)b*SS + s2)*DD + d);
        control[(size_t)b*DD + d] = c;
        if (dt) ((bf16*)out)[(size_t)b*DD + d] = f2b(c);
        else    ((float*)out)[(size_t)b*DD + d] = c;
        vb += ldin(dt, bc2, d) * c * warf[d];
    }
    red[tid] = vb; __syncthreads();
    for (int off = 128; off; off >>= 1){ if (tid < off) red[tid] += red[tid + off]; __syncthreads(); }
    if (tid == 0) bias_r[b] = red[0] + ldin(dt, bar, 0);
}

// ---------------- softmax over HW + read (fused deterministic lpart reduce, 4 slices) ----
__global__ __launch_bounds__(256) void softmax_read_k(const float* __restrict__ lpart,
                                                      const float* __restrict__ bias_r,
                                                      const void* __restrict__ know,
                                                      float* __restrict__ readout,
                                                      const int* __restrict__ flag){
    const int dt = *flag;
    const int b = blockIdx.x, tid = threadIdx.x;
    __shared__ float a[HWN];
    __shared__ float red[256];
    float x = -INFINITY;
    if (tid < HWN){
        float sacc = bias_r[b];
        #pragma unroll
        for (int c = 0; c < 4; ++c)
            sacc += lpart[(size_t)c * (BB * HWN) + (size_t)b * HWN + tid];
        x = sacc;
    }
    red[tid] = x; __syncthreads();
    for (int off = 128; off; off >>= 1){ if (tid < off) red[tid] = fmaxf(red[tid], red[tid + off]); __syncthreads(); }
    float mx = red[0]; __syncthreads();
    float e = (tid < HWN) ? expf(x - mx) : 0.f;
    red[tid] = e; __syncthreads();
    for (int off = 128; off; off >>= 1){ if (tid < off) red[tid] += red[tid + off]; __syncthreads(); }
    float inv = 1.f / red[0];
    if (tid < HWN) a[tid] = e * inv;
    __syncthreads();
    for (int d = tid; d < DD; d += 256){
        size_t base = ((size_t)b*DD + d) * HWN;
        float sum = 0.f;
        if (dt){
            const ushort4* k4 = (const ushort4*)((const unsigned short*)know + base);
            #pragma unroll 7
            for (int c = 0; c < HWN/4; ++c){
                ushort4 u4 = k4[c];
                sum += a[4*c+0]*us2f(u4.x) + a[4*c+1]*us2f(u4.y)
                     + a[4*c+2]*us2f(u4.z) + a[4*c+3]*us2f(u4.w);
            }
        } else {
            const float4* k4 = (const float4*)((const float*)know + base);
            #pragma unroll 7
            for (int c = 0; c < HWN/4; ++c){
                float4 f4 = k4[c];
                sum += a[4*c+0]*f4.x + a[4*c+1]*f4.y + a[4*c+2]*f4.z + a[4*c+3]*f4.w;
            }
        }
        readout[(size_t)b*DD + d] = sum;
    }
}

extern "C" void kernel_launch(void* const* d_in, const int* in_sizes, int n_in,
                              void* d_out, int out_size, void* d_ws, size_t ws_size,
                              hipStream_t stream){
    const void* words    = d_in[0];
    const void* question = d_in[1];
    const void* know     = d_in[2];
    const void* control0 = d_in[3];
    const void* memory0  = d_in[4];
    const void* Wsc = d_in[5];   const void* bsc = d_in[6];
    const void* Wp  = d_in[7];   const void* bp  = d_in[8];
    const void* Wcq = d_in[9];   const void* bcq = d_in[10];
    const void* wac = d_in[11];  const void* bac = d_in[12];
    const void* Wm  = d_in[13];  const void* bm  = d_in[14];
    const void* Wk  = d_in[15];  const void* bk  = d_in[16];
    const void* Wc1 = d_in[17];  const void* bc1 = d_in[18];
    const void* Wc2 = d_in[19];  const void* bc2 = d_in[20];
    const void* war = d_in[21];  const void* bar = d_in[22];
    // d_in[23..26] dead: softmax over singleton axis == 1 => attn_mem == memory0
    const void* Wwcat = d_in[27]; const void* bwcat = d_in[28];

    int* flag = (int*)d_ws;
    float* F = ((float*)d_ws) + 16;
    const int NBD = BB * DD;
    float* q_   = F;
    float* pa   = F + 1*NBD;
    float* cq   = F + 2*NBD;
    float* ctrl = F + 3*NBD;
    float* pm   = F + 4*NBD;
    float* t3b  = F + 5*NBD;
    float* u_   = F + 6*NBD;
    float* rd   = F + 7*NBD;
    float* nm   = F + 8*NBD;
    float* bias_r = F + 9*NBD;                  // [B]
    float* warf   = bias_r + BB;                // [D]
    float* bkf    = warf + DD;                  // [D]
    float* lpart  = bkf + DD;                   // [4][B*HW] (alloc 8 for headroom)
    size_t off_f = 16 + 9*(size_t)NBD + BB + 2*DD + 8*(size_t)BB*HWN;
    size_t byte_off = (off_f * 4 + 255) & ~(size_t)255;
    bf16* WB = (bf16*)((char*)d_ws + byte_off);
    bf16* WscT   = WB;                          // [512][1024]
    bf16* WcqT   = WscT  + (size_t)DD*2*DD;     // [512][1024]
    bf16* Wc1T2  = WcqT  + (size_t)DD*2*DD;     // [512][1024]
    bf16* WwcatF = Wc1T2 + (size_t)DD*2*DD;     // [512][1024]
    bf16* WpT    = WwcatF+ (size_t)DD*2*DD;     // [512][512]
    bf16* WmT    = WpT   + (size_t)DD*DD;
    bf16* Wc1t3T = WmT   + (size_t)DD*DD;
    bf16* WkT    = Wc1t3T+ (size_t)DD*DD;
    bf16* Wc2cv  = WkT   + (size_t)DD*DD;
    size_t big_off = (byte_off + ((size_t)DD*2*DD*4 + (size_t)DD*DD*5) * sizeof(bf16) + 255) & ~(size_t)255;

    size_t per_batch = (size_t)HWN * 1024 * sizeof(bf16);       // A2 rows: [196][1024] bf16
    size_t avail = (ws_size > big_off) ? (ws_size - big_off) : 0;
    int CB = (int)(avail / per_batch);
    CB &= ~31;                                                  // multiple of 32
    if (CB > BB) CB = BB;
    if (CB < 32) CB = 32;
    bf16* A2 = (bf16*)((char*)d_ws + big_off);                  // [CB*196][1024]

    dim3 blk(256);

    detect_k<<<dim3(1), blk, 0, stream>>>(question, flag);

    // ---- fused weight prep (single launch, runtime dt) ----
    {
        PrepP P; int bo = 0;
        auto J = [&](const void* s, const void* sb, const void* s2, const void* s2b,
                     bf16* d, int R, int C, int ldd, int kofs, int mode, int idx){
            int nb = (mode == 3) ? 1 : ((R >> 5) * (C >> 5));
            P.j[idx] = PJob{ s, sb, s2, s2b, d, R, C, ldd, kofs, mode, bo };
            bo += nb;
        };
        const void* Wc1t3_f = (const void*)((const float*)Wc1 + (size_t)2*DD*DD);
        const void* Wc1t3_b = (const void*)((const bf16*) Wc1 + (size_t)2*DD*DD);
        const void* Ww1_f = (const void*)((const float*)Wwcat + (size_t)DD*DD);
        const void* Ww1_b = (const void*)((const bf16*) Wwcat + (size_t)DD*DD);
        const void* Ww2_f = (const void*)((const float*)Wwcat + (size_t)2*DD*DD);
        const void* Ww2_b = (const void*)((const bf16*) Wwcat + (size_t)2*DD*DD);
        J(Wsc,   Wsc,   nullptr, nullptr, WscT,   2*DD, DD, 2*DD, 0,   0, 0);
        J(Wp,    Wp,    nullptr, nullptr, WpT,    DD,   DD, DD,   0,   0, 1);
        J(Wcq,   Wcq,   nullptr, nullptr, WcqT,   2*DD, DD, 2*DD, 0,   0, 2);
        J(Wm,    Wm,    nullptr, nullptr, WmT,    DD,   DD, DD,   0,   0, 3);
        J(Wc1,   Wc1,   nullptr, nullptr, Wc1T2,  2*DD, DD, 2*DD, 0,   0, 4);
        J(Wc1t3_f, Wc1t3_b, nullptr, nullptr, Wc1t3T, DD, DD, DD, 0,   0, 5);
        J(Wk,    Wk,    nullptr, nullptr, WkT,    DD,   DD, DD,   0,   0, 6);
        J(Wwcat, Wwcat, nullptr, nullptr, WwcatF, DD,   DD, 2*DD, 0,   0, 7);
        J(Ww1_f, Ww1_b, Ww2_f,   Ww2_b,   WwcatF, DD,   DD, 2*DD, 512, 1, 8);
        J(Wc2,   Wc2,   nullptr, nullptr, Wc2cv,  DD,   DD, DD,   0,   2, 9);
        J(nullptr,nullptr,nullptr,nullptr,nullptr,0,    0,  0,    0,   3, 10);
        P.war = war; P.bk = bk; P.warf = warf; P.bkf = bkf;
        prep_k<<<dim3(bo), blk, 0, stream>>>(P, flag);
    }

    SPP P2;
    auto mkjob = [&](SP& p){ p = SP{}; };

    // launch 1: q = tanh(question @ Wsc + bsc)  ||  pm = memory0 @ Wm + bm
    mkjob(P2.j[0]);
    P2.j[0].nseg = 1;
    P2.j[0].s[0] = SSeg{ question, 0, 2*DD, 2*DD, 0 };
    P2.j[0].BT = WscT; P2.j[0].ldb = 2*DD;
    P2.j[0].bias = bsc; P2.j[0].C = q_; P2.j[0].M = BB; P2.j[0].N = DD; P2.j[0].act = 1;
    mkjob(P2.j[1]);
    P2.j[1].nseg = 1;
    P2.j[1].s[0] = SSeg{ memory0, 0, DD, DD, 0 };
    P2.j[1].BT = WmT; P2.j[1].ldb = DD;
    P2.j[1].bias = bm; P2.j[1].C = pm; P2.j[1].M = BB; P2.j[1].N = DD; P2.j[1].act = 0;
    sgemm_k<<<dim3(DD/16, BB/64, 2), blk, 0, stream>>>(P2, flag);

    // launch 2: pa = q @ Wp + bp  ||  t3b = pm @ Wc1[2D:3D] + bc1
    mkjob(P2.j[0]);
    P2.j[0].nseg = 1;
    P2.j[0].s[0] = SSeg{ q_, 1, DD, DD, 0 };
    P2.j[0].BT = WpT; P2.j[0].ldb = DD;
    P2.j[0].bias = bp; P2.j[0].C = pa; P2.j[0].M = BB; P2.j[0].N = DD; P2.j[0].act = 0;
    mkjob(P2.j[1]);
    P2.j[1].nseg = 1;
    P2.j[1].s[0] = SSeg{ pm, 1, DD, DD, 0 };
    P2.j[1].BT = Wc1t3T; P2.j[1].ldb = DD;
    P2.j[1].bias = bc1; P2.j[1].C = t3b; P2.j[1].M = BB; P2.j[1].N = DD; P2.j[1].act = 0;
    sgemm_k<<<dim3(DD/16, BB/64, 2), blk, 0, stream>>>(P2, flag);

    // launch 3: cq = [control0, pa] @ Wcq + bcq
    mkjob(P2.j[0]);
    P2.j[0].nseg = 2;
    P2.j[0].s[0] = SSeg{ control0, 0, DD, DD, 0 };
    P2.j[0].s[1] = SSeg{ pa,       1, DD, DD, 512 };
    P2.j[0].BT = WcqT; P2.j[0].ldb = 2*DD;
    P2.j[0].bias = bcq; P2.j[0].C = cq; P2.j[0].M = BB; P2.j[0].N = DD; P2.j[0].act = 0;
    sgemm_k<<<dim3(DD/16, BB/64, 1), blk, 0, stream>>>(P2, flag);

    // control (+ fused bias_r, + writes first half of d_out)
    attn_control_k<<<dim3(BB), blk, 0, stream>>>(cq, wac, bac, words, ctrl,
                                                 bc2, warf, bar, bias_r, d_out, flag);

    // u[b,e] = sum_d Wc2[e,d] * (ctrl[b,d]*war[d])
    mkjob(P2.j[0]);
    P2.j[0].nseg = 1;
    P2.j[0].s[0] = SSeg{ ctrl, 1, DD, DD, 0 };
    P2.j[0].BT = Wc2cv; P2.j[0].ldb = DD; P2.j[0].amul = warf;
    P2.j[0].C = u_; P2.j[0].M = BB; P2.j[0].N = DD; P2.j[0].act = 0;
    sgemm_k<<<dim3(DD/16, BB/64, 1), blk, 0, stream>>>(P2, flag);

    // chunked MFMA pipeline: G1 (know-transpose gather, writes A2=[pk*pm|pk]) -> G2 (K=1024)
    for (int b0 = 0; b0 < BB; b0 += CB){
        int cb = (b0 + CB <= BB) ? CB : (BB - b0);
        int nR = cb * 49 / 32;                      // (cb*196)/128 r-tiles
        int swzf = (nR % 8 == 0) ? 1 : 0;
        g1_mfma<<<dim3(nR * 4), blk, 0, stream>>>(know, WkT, bkf, pm, A2, b0, swzf, flag);
        g2_mfma<<<dim3(nR * 4), blk, 0, stream>>>(A2, Wc1T2, t3b, u_, lpart, b0, swzf);
    }

    // softmax + read (fused deterministic lpart reduce)
    softmax_read_k<<<dim3(BB), blk, 0, stream>>>(lpart, bias_r, know, rd, flag);

    // next_mem = [rd, memory0] @ WwcatF^T + bwcat  (writes second half of d_out directly)
    mkjob(P2.j[0]);
    P2.j[0].nseg = 2;
    P2.j[0].s[0] = SSeg{ rd,      1, DD, DD, 0 };
    P2.j[0].s[1] = SSeg{ memory0, 0, DD, DD, 512 };
    P2.j[0].BT = WwcatF; P2.j[0].ldb = 2*DD;
    P2.j[0].bias = bwcat; P2.j[0].C = nm; P2.j[0].M = BB; P2.j[0].N = DD; P2.j[0].act = 0;
    P2.j[0].out2 = d_out; P2.j[0].o2off = NBD;
    sgemm_k<<<dim3(DD/16, BB/64, 1), blk, 0, stream>>>(P2, flag);
}